// Round 1
// 6696.656 us; speedup vs baseline: 6.1193x; 6.1193x over previous
//
#include <hip/hip_runtime.h>
#include <hip/hip_cooperative_groups.h>
#include <math.h>

namespace cg = cooperative_groups;

struct Ptr8 { const float* p[8]; };

#define Bn 4096
#define Kn 3000
#define KQ4 750
#define KP 3072
#define INV_EPS 20.0f
#define INV_TEMP 10.0f
#define TINYF 1e-12f
#define TOLF 1e-3f
#define TGTC (4096.0f/3000.0f)

// sparse config: keep s >= rowmax - CUTF  (q >= e^-28 ~ 7e-13)
#define CAPR 448
#define CAPC 448
#define CUTF 1.4f

// build kernel: one wave per (crop,row) -> 2*4096 waves = 2048 blocks
#define BLD_NBLK 2048

// iterate kernel: small cooperative grid (sync cost ~ #blocks)
#define IT_NBLK 64
#define IT_THR 512
#define IT_WPB (IT_THR / 64)
#define IT_NW (IT_NBLK * IT_WPB)

// dense fallback config (round-0)
#define NSTR 12
#define NCH 40
#define GRID_S 480
#define NW_S (GRID_S * 4)

__device__ __forceinline__ float wsum(float x) {
#pragma unroll
  for (int o = 32; o; o >>= 1) x += __shfl_xor(x, o, 64);
  return x;
}
__device__ __forceinline__ float wmax(float x) {
#pragma unroll
  for (int o = 32; o; o >>= 1) x = fmaxf(x, __shfl_xor(x, o, 64));
  return x;
}
// 4-wave block max (256-thread kernels)
__device__ __forceinline__ float block_max(float x) {
  __shared__ float s[4];
  x = wmax(x);
  if ((threadIdx.x & 63) == 0) s[threadIdx.x >> 6] = x;
  __syncthreads();
  float r = fmaxf(fmaxf(s[0], s[1]), fmaxf(s[2], s[3]));
  __syncthreads();
  return r;
}
// 8-wave block max (512-thread iterate kernel)
__device__ __forceinline__ float block_max8(float x) {
  __shared__ float s8[8];
  x = wmax(x);
  if ((threadIdx.x & 63) == 0) s8[threadIdx.x >> 6] = x;
  __syncthreads();
  float r = s8[0];
#pragma unroll
  for (int i = 1; i < 8; ++i) r = fmaxf(r, s8[i]);
  __syncthreads();
  return r;
}

// ---------------------------------------------------------------------------
// Build kernel (non-cooperative): per (crop,row) wave computes row max m,
// r0 = sum exp((s-m)*INV_EPS), then builds CSR+CSC of q for s >= m - CUTF.
// Row (12 KB) stays L1/L2-hot across the three scans -> no global sync needed.
// ---------------------------------------------------------------------------
struct BuildArgs {
  Ptr8 ptrs;
  const int* iap; const int* ibp;
  float* pmA; float* pmB;            // row max (persist slot m) per crop
  float* r;                          // [2*Bn] r0 then running Q@v
  unsigned* rowcnt;                  // [2*Bn]
  unsigned* colcnt;                  // [2*KP], must be pre-zeroed
  float* csrq; unsigned short* csridx;   // [2*Bn*CAPR]
  float* cscq; unsigned short* cscidx;   // [2*KP*CAPC]
};

__global__ __launch_bounds__(256, 2) void build_sparse(BuildArgs a) {
  const int tid = threadIdx.x;
  const int lane = tid & 63;
  const int wv = blockIdx.x * 4 + (tid >> 6);   // 0..8191
  const int crop = wv >> 12;                    // 0 or 1
  const int row = wv & (Bn - 1);
  const int idx = ((crop ? *a.ibp : *a.iap) & 7);
  const float* __restrict__ lg = a.ptrs.p[idx];
  const float4* rp = (const float4*)(lg + (size_t)row * Kn);

  // pass 1: streaming max + rescaled sum
  float M = -INFINITY, T = 0.f;
  for (int i = lane; i < KQ4; i += 64) {
    float4 x = rp[i];
    float m4 = fmaxf(fmaxf(x.x, x.y), fmaxf(x.z, x.w));
    float t4 = __expf((x.x - m4) * INV_EPS) + __expf((x.y - m4) * INV_EPS)
             + __expf((x.z - m4) * INV_EPS) + __expf((x.w - m4) * INV_EPS);
    float Mn = fmaxf(M, m4);
    T = T * __expf((M - Mn) * INV_EPS) + t4 * __expf((m4 - Mn) * INV_EPS);
    M = Mn;
  }
#pragma unroll
  for (int o = 32; o; o >>= 1) {
    float M2 = __shfl_xor(M, o, 64);
    float T2 = __shfl_xor(T, o, 64);
    float Mn = fmaxf(M, M2);
    T = T * __expf((M - Mn) * INV_EPS) + T2 * __expf((M2 - Mn) * INV_EPS);
    M = Mn;
  }
  if (lane == 0) {
    (crop ? a.pmB : a.pmA)[row] = M;
    a.r[crop * Bn + row] = T;
  }
  const float thr = M - CUTF;

  // pass 2: count kept entries per lane -> exclusive scan for CSR slots
  int cnt = 0;
  for (int i = lane; i < KQ4; i += 64) {
    float4 x = rp[i];
    cnt += (x.x >= thr) + (x.y >= thr) + (x.z >= thr) + (x.w >= thr);
  }
  int incl = cnt;
#pragma unroll
  for (int o = 1; o < 64; o <<= 1) {
    int t = __shfl_up(incl, o, 64);
    if (lane >= o) incl += t;
  }
  int total = __shfl(incl, 63, 64);
  int p = incl - cnt;
  if (lane == 0) a.rowcnt[crop * Bn + row] = (unsigned)min(total, CAPR);

  float* crow = a.csrq + ((size_t)crop * Bn + row) * CAPR;
  unsigned short* cidx = a.csridx + ((size_t)crop * Bn + row) * CAPR;
  unsigned* ccnt = a.colcnt + crop * KP;
  float* cq_ = a.cscq + (size_t)crop * KP * CAPC;
  unsigned short* ci_ = a.cscidx + (size_t)crop * KP * CAPC;

  // pass 3: emit
  for (int i = lane; i < KQ4; i += 64) {
    float4 x = rp[i];
    int k0 = i * 4;
#define EMIT(val, kk)                                                          \
    if ((val) >= thr) {                                                        \
      float q = __expf(((val) - M) * INV_EPS);                                 \
      if (p < CAPR) { crow[p] = q; cidx[p] = (unsigned short)(kk); }           \
      unsigned slot = atomicAdd(&ccnt[kk], 1u);                                \
      if (slot < CAPC) {                                                       \
        size_t o2 = (size_t)(kk) * CAPC + slot;                                \
        cq_[o2] = q; ci_[o2] = (unsigned short)row;                            \
      }                                                                        \
      ++p;                                                                     \
    }
    EMIT(x.x, k0 + 0) EMIT(x.y, k0 + 1) EMIT(x.z, k0 + 2) EMIT(x.w, k0 + 3)
#undef EMIT
  }
}

// ---------------------------------------------------------------------------
// Iterate kernel (cooperative, small grid): runs BOTH crops' sinkhorn loops
// concurrently; per-crop done flags freeze each crop's state at exactly its
// reference convergence iteration. 2 grid.syncs per iteration amortized
// across both crops.
// ---------------------------------------------------------------------------
struct ItArgs {
  float* pAa; float* pCa; float* pAb; float* pCb;   // persist A/C per crop
  float* u; float* r; float* v; float* alpha;       // [2*Bn]/[2*Bn]/[2*KP]/[2*Bn]
  const unsigned* rowcnt; const unsigned* colcnt;
  const float* csrq; const unsigned short* csridx;
  const float* cscq; const unsigned short* cscidx;
  unsigned* errA; unsigned* errB;
};

__global__ __launch_bounds__(IT_THR, 2) void sinkhorn_iterate(ItArgs a) {
  cg::grid_group grid = cg::this_grid();
  const int tid = threadIdx.x;
  const int lane = tid & 63;
  const int wv = blockIdx.x * IT_WPB + (tid >> 6);

  bool done0 = false, done1 = false;
  int it = 0;
  while (true) {
    ++it;
    // ---- col pass: v_k = tgt / (sum_b q/(r_b+TINY) + TINY), fused err
    float cerr0 = 0.f, cerr1 = 0.f;
    for (int vc = wv; vc < 2 * Kn; vc += IT_NW) {
      int crop = vc >= Kn;
      if (crop ? done1 : done0) continue;
      int col = vc - crop * Kn;
      const float* cq = a.cscq + ((size_t)crop * KP + col) * CAPC;
      const unsigned short* ci = a.cscidx + ((size_t)crop * KP + col) * CAPC;
      const float* rr = a.r + crop * Bn;
      int n = min((int)a.colcnt[crop * KP + col], CAPC);
      float acc = 0.f;
      for (int j = lane; j < n; j += 64) acc += cq[j] / (rr[ci[j]] + TINYF);
      acc = wsum(acc);
      float vk = TGTC / (acc + TINYF);
      if (lane == 0) a.v[crop * KP + col] = vk;
      float e = fabsf(vk * acc - TGTC);
      if (crop) cerr1 = fmaxf(cerr1, e); else cerr0 = fmaxf(cerr0, e);
    }
    {
      float b0 = block_max8(cerr0);
      float b1 = block_max8(cerr1);
      if (tid == 0) {
        if (!done0) atomicMax(&a.errA[2 * it + 1], __float_as_uint(b0));
        if (!done1) atomicMax(&a.errB[2 * it + 1], __float_as_uint(b1));
      }
    }
    __threadfence();
    grid.sync();
    // ---- row pass: r_new = Q @ v ; store u used this iteration ; err
    float lerr0 = 0.f, lerr1 = 0.f;
    for (int vr = wv; vr < 2 * Bn; vr += IT_NW) {
      int crop = vr >= Bn;
      if (crop ? done1 : done0) continue;
      int row = vr - crop * Bn;
      const float* rq = a.csrq + ((size_t)crop * Bn + row) * CAPR;
      const unsigned short* ri = a.csridx + ((size_t)crop * Bn + row) * CAPR;
      const float* vv = a.v + crop * KP;
      int n = min((int)a.rowcnt[crop * Bn + row], CAPR);
      float acc = 0.f;
      for (int j = lane; j < n; j += 64) acc += rq[j] * vv[ri[j]];
      acc = wsum(acc);
      float uu = 1.0f / (a.r[crop * Bn + row] + TINYF);
      if (lane == 0) { a.u[crop * Bn + row] = uu; a.r[crop * Bn + row] = acc; }
      float e = fabsf(uu * acc - 1.0f);
      if (crop) lerr1 = fmaxf(lerr1, e); else lerr0 = fmaxf(lerr0, e);
    }
    {
      float b0 = block_max8(lerr0);
      float b1 = block_max8(lerr1);
      if (tid == 0) {
        if (!done0) atomicMax(&a.errA[2 * it], __float_as_uint(b0));
        if (!done1) atomicMax(&a.errB[2 * it], __float_as_uint(b1));
      }
    }
    __threadfence();
    grid.sync();
    // ---- per-crop convergence decision (uniform across all threads)
    if (!done0) {
      unsigned rb = __hip_atomic_load(&a.errA[2 * it], __ATOMIC_RELAXED, __HIP_MEMORY_SCOPE_AGENT);
      unsigned cb = __hip_atomic_load(&a.errA[2 * it + 1], __ATOMIC_RELAXED, __HIP_MEMORY_SCOPE_AGENT);
      float err = fmaxf(__uint_as_float(rb), __uint_as_float(cb));
      done0 = (it >= 3) && (it >= 100 || err <= TOLF);
    }
    if (!done1) {
      unsigned rb = __hip_atomic_load(&a.errB[2 * it], __ATOMIC_RELAXED, __HIP_MEMORY_SCOPE_AGENT);
      unsigned cb = __hip_atomic_load(&a.errB[2 * it + 1], __ATOMIC_RELAXED, __HIP_MEMORY_SCOPE_AGENT);
      float err = fmaxf(__uint_as_float(rb), __uint_as_float(cb));
      done1 = (it >= 3) && (it >= 100 || err <= TOLF);
    }
    if (done0 && done1) break;
  }

  // ---- final normalization: alpha, then C, then A (P = q * A_b * C_k)
  for (int g = blockIdx.x * IT_THR + tid; g < 2 * Bn; g += IT_NBLK * IT_THR) {
    float uu = a.u[g], rr = a.r[g];
    a.alpha[g] = uu / fmaxf(uu * rr, TINYF);
  }
  __threadfence();
  grid.sync();
  for (int vc = wv; vc < 2 * Kn; vc += IT_NW) {
    int crop = vc >= Kn;
    int col = vc - crop * Kn;
    const float* cq = a.cscq + ((size_t)crop * KP + col) * CAPC;
    const unsigned short* ci = a.cscidx + ((size_t)crop * KP + col) * CAPC;
    const float* al = a.alpha + crop * Bn;
    int n = min((int)a.colcnt[crop * KP + col], CAPC);
    float d = 0.f;
    for (int j = lane; j < n; j += 64) d += cq[j] * al[ci[j]];
    d = wsum(d);
    float vk = a.v[crop * KP + col];
    if (lane == 0)
      (crop ? a.pCb : a.pCa)[col] = vk * TGTC / fmaxf(vk * d, TINYF);
  }
  __threadfence();
  grid.sync();
  for (int vr = wv; vr < 2 * Bn; vr += IT_NW) {
    int crop = vr >= Bn;
    int row = vr - crop * Bn;
    const float* rq = a.csrq + ((size_t)crop * Bn + row) * CAPR;
    const unsigned short* ri = a.csridx + ((size_t)crop * Bn + row) * CAPR;
    const float* pc = crop ? a.pCb : a.pCa;
    int n = min((int)a.rowcnt[crop * Bn + row], CAPR);
    float e = 0.f;
    for (int j = lane; j < n; j += 64) e += rq[j] * pc[ri[j]];
    e = wsum(e);
    if (lane == 0) {
      float al = a.alpha[crop * Bn + row];
      (crop ? a.pAb : a.pAa)[row] = al / fmaxf(al * e, TINYF);
    }
  }
}

// ---------------------------------------------------------------------------
// Dense fallback (round-0 kernel), used only if ws_size is too small.
// ---------------------------------------------------------------------------
__global__ __launch_bounds__(256, 2) void sinkhorn_dense(
    Ptr8 ptrs, const int* __restrict__ idxp,
    float* __restrict__ ws_m, float* __restrict__ ws_u, float* __restrict__ ws_r,
    float* __restrict__ ws_A, float* __restrict__ ws_v, float* __restrict__ ws_C,
    float* __restrict__ cpart, unsigned* __restrict__ errbuf)
{
  cg::grid_group grid = cg::this_grid();
  const int idx = (*idxp) & 7;
  const float* __restrict__ lg = ptrs.p[idx];
  const int tid = threadIdx.x;
  const int lane = tid & 63;
  const int gw = blockIdx.x * 4 + (tid >> 6);
  const int stripe = blockIdx.x % NSTR;
  const int chunk = blockIdx.x / NSTR;
  const int kcol = stripe * 256 + tid;
  const int rs = (chunk * Bn) / NCH;
  const int re = ((chunk + 1) * Bn) / NCH;

  for (int row = gw; row < Bn; row += NW_S) {
    const float4* rp = (const float4*)(lg + (size_t)row * Kn);
    float M = -INFINITY, T = 0.f;
    for (int i = lane; i < KQ4; i += 64) {
      float4 x = rp[i];
      float m4 = fmaxf(fmaxf(x.x, x.y), fmaxf(x.z, x.w));
      float t4 = __expf((x.x - m4) * INV_EPS) + __expf((x.y - m4) * INV_EPS)
               + __expf((x.z - m4) * INV_EPS) + __expf((x.w - m4) * INV_EPS);
      float Mn = fmaxf(M, m4);
      T = T * __expf((M - Mn) * INV_EPS) + t4 * __expf((m4 - Mn) * INV_EPS);
      M = Mn;
    }
#pragma unroll
    for (int o = 32; o; o >>= 1) {
      float M2 = __shfl_xor(M, o, 64);
      float T2 = __shfl_xor(T, o, 64);
      float Mn = fmaxf(M, M2);
      T = T * __expf((M - Mn) * INV_EPS) + T2 * __expf((M2 - Mn) * INV_EPS);
      M = Mn;
    }
    if (lane == 0) { ws_m[row] = M; ws_r[row] = T; }
  }
  grid.sync(); __threadfence();

  int it = 0;
  while (true) {
    ++it;
    {
      float acc = 0.f;
      if (kcol < Kn) {
        for (int row = rs; row < re; ++row) {
          float u = 1.0f / (ws_r[row] + TINYF);
          acc += u * __expf((lg[(size_t)row * Kn + kcol] - ws_m[row]) * INV_EPS);
        }
      }
      cpart[chunk * KP + stripe * 256 + tid] = acc;
    }
    grid.sync(); __threadfence();
    {
      int k = blockIdx.x * 256 + tid;
      float cerr = 0.f;
      if (k < Kn) {
        float c = 0.f;
        for (int ch = 0; ch < NCH; ++ch) c += cpart[ch * KP + k];
        float vk = TGTC / (c + TINYF);
        ws_v[k] = vk;
        cerr = fabsf(vk * c - TGTC);
      }
      float bm = block_max(cerr);
      if (tid == 0) atomicMax(&errbuf[2 * it + 1], __float_as_uint(bm));
    }
    grid.sync(); __threadfence();
    {
      float lerr = 0.f;
      for (int row = gw; row < Bn; row += NW_S) {
        const float4* rp = (const float4*)(lg + (size_t)row * Kn);
        const float4* vp = (const float4*)ws_v;
        float mm = ws_m[row];
        float u = 1.0f / (ws_r[row] + TINYF);
        float Ssum = 0.f;
        for (int i = lane; i < KQ4; i += 64) {
          float4 x = rp[i];
          float4 vv = vp[i];
          Ssum += __expf((x.x - mm) * INV_EPS) * vv.x
                + __expf((x.y - mm) * INV_EPS) * vv.y
                + __expf((x.z - mm) * INV_EPS) * vv.z
                + __expf((x.w - mm) * INV_EPS) * vv.w;
        }
        Ssum = wsum(Ssum);
        if (lane == 0) { ws_u[row] = u; ws_r[row] = Ssum; }
        lerr = fmaxf(lerr, fabsf(u * Ssum - 1.0f));
      }
      float bm = block_max(lerr);
      if (tid == 0) atomicMax(&errbuf[2 * it], __float_as_uint(bm));
    }
    grid.sync(); __threadfence();
    unsigned rbits = __hip_atomic_load(&errbuf[2 * it], __ATOMIC_RELAXED, __HIP_MEMORY_SCOPE_AGENT);
    unsigned cbits = __hip_atomic_load(&errbuf[2 * it + 1], __ATOMIC_RELAXED, __HIP_MEMORY_SCOPE_AGENT);
    float err = fmaxf(__uint_as_float(rbits), __uint_as_float(cbits));
    if (it >= 3 && (it >= 100 || err <= TOLF)) break;
  }

  {
    float acc = 0.f;
    if (kcol < Kn) {
      for (int row = rs; row < re; ++row) {
        float u = ws_u[row];
        float sp = fmaxf(u * ws_r[row], TINYF);
        acc += (u / sp) * __expf((lg[(size_t)row * Kn + kcol] - ws_m[row]) * INV_EPS);
      }
    }
    cpart[chunk * KP + stripe * 256 + tid] = acc;
  }
  grid.sync(); __threadfence();
  {
    int k = blockIdx.x * 256 + tid;
    if (k < Kn) {
      float d = 0.f;
      for (int ch = 0; ch < NCH; ++ch) d += cpart[ch * KP + k];
      float vk = ws_v[k];
      ws_C[k] = vk * TGTC / fmaxf(vk * d, TINYF);
    }
  }
  grid.sync(); __threadfence();
  {
    for (int row = gw; row < Bn; row += NW_S) {
      const float4* rp = (const float4*)(lg + (size_t)row * Kn);
      const float4* cp = (const float4*)ws_C;
      float mm = ws_m[row];
      float e = 0.f;
      for (int i = lane; i < KQ4; i += 64) {
        float4 x = rp[i];
        float4 cc = cp[i];
        e += __expf((x.x - mm) * INV_EPS) * cc.x
           + __expf((x.y - mm) * INV_EPS) * cc.y
           + __expf((x.z - mm) * INV_EPS) * cc.z
           + __expf((x.w - mm) * INV_EPS) * cc.w;
      }
      e = wsum(e);
      if (lane == 0) {
        float u = ws_u[row];
        float sp = fmaxf(u * ws_r[row], TINYF);
        float us = u / sp;
        float w = us * e;
        ws_A[row] = us / fmaxf(w, TINYF);
      }
    }
  }
}

// ---------------------------------------------------------------------------
// Fused loss/entropy/qmax pass (persist layout: m@0, A@4096, C@8192)
// ---------------------------------------------------------------------------
__global__ __launch_bounds__(256) void loss_kernel(
    Ptr8 ptrs, const int* __restrict__ iap, const int* __restrict__ ibp,
    const float* __restrict__ wsa, const float* __restrict__ wsb,
    float* __restrict__ out)
{
  const int ia = (*iap) & 7;
  const int ib = (*ibp) & 7;
  const int lane = threadIdx.x & 63;
  const int row = blockIdx.x * 4 + (threadIdx.x >> 6);

  const float ma = wsa[row];
  const float Aa = wsa[4096 + row];
  const float mb = wsb[row];
  const float Ab = wsb[4096 + row];
  const float4* Ca4 = (const float4*)(wsa + 8192);
  const float4* Cb4 = (const float4*)(wsb + 8192);
  size_t off = (size_t)row * Kn;
  const float4* X4[8];
#pragma unroll
  for (int c = 0; c < 8; ++c) X4[c] = (const float4*)(ptrs.p[c] + off);
  const float4* xa4 = (const float4*)(ptrs.p[ia] + off);
  const float4* xb4 = (const float4*)(ptrs.p[ib] + off);

  float M[8], S[8], da[8], db[8];
#pragma unroll
  for (int c = 0; c < 8; ++c) { M[c] = -INFINITY; S[c] = 0.f; da[c] = 0.f; db[c] = 0.f; }
  float enta = 0.f, entb = 0.f, ra = 0.f, rb = 0.f, qam = 0.f, qbm = 0.f;

  for (int i = lane; i < KQ4; i += 64) {
    float4 xa = xa4[i], xb = xb4[i];
    float4 ca = Ca4[i], cb = Cb4[i];
    float qa0 = __expf((xa.x - ma) * INV_EPS) * Aa * ca.x;
    float qa1 = __expf((xa.y - ma) * INV_EPS) * Aa * ca.y;
    float qa2 = __expf((xa.z - ma) * INV_EPS) * Aa * ca.z;
    float qa3 = __expf((xa.w - ma) * INV_EPS) * Aa * ca.w;
    float qb0 = __expf((xb.x - mb) * INV_EPS) * Ab * cb.x;
    float qb1 = __expf((xb.y - mb) * INV_EPS) * Ab * cb.y;
    float qb2 = __expf((xb.z - mb) * INV_EPS) * Ab * cb.z;
    float qb3 = __expf((xb.w - mb) * INV_EPS) * Ab * cb.w;
    ra += (qa0 + qa1) + (qa2 + qa3);
    rb += (qb0 + qb1) + (qb2 + qb3);
    enta += qa0 * __logf(qa0 + TINYF) + qa1 * __logf(qa1 + TINYF)
          + qa2 * __logf(qa2 + TINYF) + qa3 * __logf(qa3 + TINYF);
    entb += qb0 * __logf(qb0 + TINYF) + qb1 * __logf(qb1 + TINYF)
          + qb2 * __logf(qb2 + TINYF) + qb3 * __logf(qb3 + TINYF);
    qam = fmaxf(qam, fmaxf(fmaxf(qa0, qa1), fmaxf(qa2, qa3)));
    qbm = fmaxf(qbm, fmaxf(fmaxf(qb0, qb1), fmaxf(qb2, qb3)));
#pragma unroll
    for (int c = 0; c < 8; ++c) {
      float4 x = X4[c][i];
      float y0 = x.x * INV_TEMP, y1 = x.y * INV_TEMP;
      float y2 = x.z * INV_TEMP, y3 = x.w * INV_TEMP;
      float m4 = fmaxf(fmaxf(y0, y1), fmaxf(y2, y3));
      float t4 = __expf(y0 - m4) + __expf(y1 - m4) + __expf(y2 - m4) + __expf(y3 - m4);
      float Mn = fmaxf(M[c], m4);
      S[c] = S[c] * __expf(M[c] - Mn) + t4 * __expf(m4 - Mn);
      M[c] = Mn;
      da[c] += qa0 * x.x + qa1 * x.y + qa2 * x.z + qa3 * x.w;
      db[c] += qb0 * x.x + qb1 * x.y + qb2 * x.z + qb3 * x.w;
    }
  }

#pragma unroll
  for (int c = 0; c < 8; ++c) {
#pragma unroll
    for (int o = 32; o; o >>= 1) {
      float M2 = __shfl_xor(M[c], o, 64);
      float S2 = __shfl_xor(S[c], o, 64);
      float Mn = fmaxf(M[c], M2);
      S[c] = S[c] * __expf(M[c] - Mn) + S2 * __expf(M2 - Mn);
      M[c] = Mn;
    }
    da[c] = wsum(da[c]);
    db[c] = wsum(db[c]);
  }
  enta = wsum(enta); entb = wsum(entb);
  ra = wsum(ra); rb = wsum(rb);
  qam = wmax(qam); qbm = wmax(qbm);

  if (lane == 0) {
    float lsum = 0.f;
    int nt = 0;
#pragma unroll
    for (int c = 0; c < 8; ++c) {
      float L = M[c] + __logf(S[c]);
      if (c != ia) { lsum -= INV_TEMP * da[c] - L * ra; ++nt; }
      if (c != ib) { lsum -= INV_TEMP * db[c] - L * rb; ++nt; }
    }
    atomicAdd(&out[0], lsum / ((float)nt * (float)Bn));
    atomicAdd(&out[1], -0.5f / (float)Bn * (enta + entb));
    atomicAdd(&out[2], 0.5f / (float)Bn * (qam + qbm));
  }
}

// ---------------------------------------------------------------------------
extern "C" void kernel_launch(void* const* d_in, const int* in_sizes, int n_in,
                              void* d_out, int out_size, void* d_ws, size_t ws_size,
                              hipStream_t stream)
{
  (void)in_sizes; (void)n_in; (void)out_size;
  Ptr8 ptrs;
  for (int c = 0; c < 8; ++c) ptrs.p[c] = (const float*)d_in[c];
  const int* iap = (const int*)d_in[8];
  const int* ibp = (const int*)d_in[9];
  float* ws = (float*)d_ws;
  float* out = (float*)d_out;

  // float-offset layout (two-crop concurrent)
  float* PA = ws;                         // m,A,C persist crop a (11264)
  float* PB = ws + 11264;                 // persist crop b
  float* u_ = ws + 22528;                 // [2*Bn]
  float* r_ = ws + 30720;                 // [2*Bn]
  float* v_ = ws + 38912;                 // [2*KP]
  float* al = ws + 45056;                 // [2*Bn]
  unsigned* rowcnt = (unsigned*)(ws + 53248);   // [2*Bn]
  unsigned* colcnt = (unsigned*)(ws + 61440);   // [2*KP]
  unsigned* errA = (unsigned*)(ws + 67584);     // 512
  unsigned* errB = (unsigned*)(ws + 68096);     // 512
  float* csrq = ws + 68608;                               // 2*4096*448
  unsigned short* csridx = (unsigned short*)(ws + 3738624);   // 2*4096*448 u16
  float* cscq = ws + 5573632;                             // 2*3072*448
  unsigned short* cscidx = (unsigned short*)(ws + 8326144);   // 2*3072*448 u16
  const size_t need_bytes = (size_t)9702400 * 4;          // 38.8 MB

  // zero colcnt + err buffers (contiguous: 6144 + 1024 uints @ ws+61440)
  hipMemsetAsync(colcnt, 0, 7168 * sizeof(unsigned), stream);
  hipMemsetAsync(d_out, 0, 3 * sizeof(float), stream);

  if (ws_size >= need_bytes) {
    BuildArgs ba;
    ba.ptrs = ptrs; ba.iap = iap; ba.ibp = ibp;
    ba.pmA = PA; ba.pmB = PB;
    ba.r = r_;
    ba.rowcnt = rowcnt; ba.colcnt = colcnt;
    ba.csrq = csrq; ba.csridx = csridx; ba.cscq = cscq; ba.cscidx = cscidx;
    hipLaunchKernelGGL(build_sparse, dim3(BLD_NBLK), dim3(256), 0, stream, ba);

    ItArgs ia;
    ia.pAa = PA + 4096; ia.pCa = PA + 8192;
    ia.pAb = PB + 4096; ia.pCb = PB + 8192;
    ia.u = u_; ia.r = r_; ia.v = v_; ia.alpha = al;
    ia.rowcnt = rowcnt; ia.colcnt = colcnt;
    ia.csrq = csrq; ia.csridx = csridx; ia.cscq = cscq; ia.cscidx = cscidx;
    ia.errA = errA; ia.errB = errB;
    void* args1[] = { (void*)&ia };
    hipLaunchCooperativeKernel((const void*)sinkhorn_iterate, dim3(IT_NBLK), dim3(IT_THR),
                               (void**)args1, 0u, stream);
  } else {
    // dense fallback (round-0 path); cpart reuses the csrq region start
    float* cpart = ws + 68608;   // NCH*KP = 122880 floats
    {
      float* m = PA; float* A = PA + 4096; float* C = PA + 8192;
      void* args[] = { (void*)&ptrs, (void*)&iap, (void*)&m, (void*)&u_, (void*)&r_,
                       (void*)&A, (void*)&v_, (void*)&C, (void*)&cpart, (void*)&errA };
      hipLaunchCooperativeKernel((const void*)sinkhorn_dense, dim3(GRID_S), dim3(256),
                                 (void**)args, 0u, stream);
    }
    {
      float* m = PB; float* A = PB + 4096; float* C = PB + 8192;
      void* args[] = { (void*)&ptrs, (void*)&ibp, (void*)&m, (void*)&u_, (void*)&r_,
                       (void*)&A, (void*)&v_, (void*)&C, (void*)&cpart, (void*)&errB };
      hipLaunchCooperativeKernel((const void*)sinkhorn_dense, dim3(GRID_S), dim3(256),
                                 (void**)args, 0u, stream);
    }
  }

  loss_kernel<<<dim3(Bn / 4), dim3(256), 0, stream>>>(ptrs, iap, ibp, PA, PB, out);
}

// Round 2
// 4725.996 us; speedup vs baseline: 8.6709x; 1.4170x over previous
//
#include <hip/hip_runtime.h>
#include <hip/hip_cooperative_groups.h>
#include <math.h>

namespace cg = cooperative_groups;

struct Ptr8 { const float* p[8]; };

#define Bn 4096
#define Kn 3000
#define KQ4 750
#define KP 3072
#define INV_EPS 20.0f
#define INV_TEMP 10.0f
#define TINYF 1e-12f
#define TOLF 1e-3f
#define TGTC (4096.0f/3000.0f)

// sparse config: keep s >= rowmax - CUTF  (q >= e^-28 ~ 7e-13)
#define CAPR 448
#define CAPC 448
#define CUTF 1.4f

// build kernel: one wave per (crop,row) -> 2*4096 waves = 2048 blocks
#define BLD_NBLK 2048

// iterate kernel: 64 blocks x 1024 threads = 1024 waves, custom barrier
#define IT_NBLK 64
#define IT_THR 1024
#define IT_NWAVE (IT_NBLK * IT_THR / 64)    // 1024
#define MAXC 6                               // ceil(2*Kn / IT_NWAVE)
#define MAXR 8                               // 2*Bn / IT_NWAVE

// dense fallback config (round-0)
#define NSTR 12
#define NCH 40
#define GRID_S 480
#define NW_S (GRID_S * 4)

__device__ __forceinline__ float wsum(float x) {
#pragma unroll
  for (int o = 32; o; o >>= 1) x += __shfl_xor(x, o, 64);
  return x;
}
__device__ __forceinline__ float wmax(float x) {
#pragma unroll
  for (int o = 32; o; o >>= 1) x = fmaxf(x, __shfl_xor(x, o, 64));
  return x;
}
// 4-wave block max (256-thread kernels)
__device__ __forceinline__ float block_max(float x) {
  __shared__ float s[4];
  x = wmax(x);
  if ((threadIdx.x & 63) == 0) s[threadIdx.x >> 6] = x;
  __syncthreads();
  float r = fmaxf(fmaxf(s[0], s[1]), fmaxf(s[2], s[3]));
  __syncthreads();
  return r;
}

// 16-wave dual block max (1024-thread iterate kernel)
__device__ __forceinline__ float2 block_max2_16(float x0, float x1, float2* sh) {
  x0 = wmax(x0); x1 = wmax(x1);
  if ((threadIdx.x & 63) == 0) sh[threadIdx.x >> 6] = make_float2(x0, x1);
  __syncthreads();
  float m0 = sh[0].x, m1 = sh[0].y;
#pragma unroll
  for (int i = 1; i < 16; ++i) { m0 = fmaxf(m0, sh[i].x); m1 = fmaxf(m1, sh[i].y); }
  __syncthreads();
  return make_float2(m0, m1);
}

// Fast grid barrier: bar[0]=arrive count, bar[1]=generation (both pre-zeroed).
// Agent-scope acquire/release + __threadfence for cross-XCD visibility.
__device__ __forceinline__ void gbar(unsigned* bar, unsigned& genl) {
  __syncthreads();
  if (threadIdx.x == 0) {
    unsigned g = ++genl;
    __threadfence();
    unsigned arr = __hip_atomic_fetch_add(&bar[0], 1u, __ATOMIC_ACQ_REL, __HIP_MEMORY_SCOPE_AGENT);
    if (arr == IT_NBLK - 1) {
      __hip_atomic_store(&bar[0], 0u, __ATOMIC_RELAXED, __HIP_MEMORY_SCOPE_AGENT);
      __hip_atomic_store(&bar[1], g, __ATOMIC_RELEASE, __HIP_MEMORY_SCOPE_AGENT);
    } else {
      while ((int)(__hip_atomic_load(&bar[1], __ATOMIC_ACQUIRE, __HIP_MEMORY_SCOPE_AGENT) - g) < 0)
        __builtin_amdgcn_s_sleep(1);
    }
    __threadfence();
  }
  __syncthreads();
}

// ---------------------------------------------------------------------------
// Build kernel (non-cooperative): per (crop,row) wave computes row max m,
// r0 = sum exp((s-m)*INV_EPS), rinv0 = 1/(r0+TINY), then CSR+CSC of q.
// ---------------------------------------------------------------------------
struct BuildArgs {
  Ptr8 ptrs;
  const int* iap; const int* ibp;
  float* pmA; float* pmB;
  float* r; float* rinv;             // [2*Bn]
  unsigned* rowcnt;                  // [2*Bn]
  unsigned* colcnt;                  // [2*KP], pre-zeroed
  float* csrq; unsigned short* csridx;
  float* cscq; unsigned short* cscidx;
};

__global__ __launch_bounds__(256, 2) void build_sparse(BuildArgs a) {
  const int tid = threadIdx.x;
  const int lane = tid & 63;
  const int wv = blockIdx.x * 4 + (tid >> 6);
  const int crop = wv >> 12;
  const int row = wv & (Bn - 1);
  const int idx = ((crop ? *a.ibp : *a.iap) & 7);
  const float* __restrict__ lg = a.ptrs.p[idx];
  const float4* rp = (const float4*)(lg + (size_t)row * Kn);

  float M = -INFINITY, T = 0.f;
  for (int i = lane; i < KQ4; i += 64) {
    float4 x = rp[i];
    float m4 = fmaxf(fmaxf(x.x, x.y), fmaxf(x.z, x.w));
    float t4 = __expf((x.x - m4) * INV_EPS) + __expf((x.y - m4) * INV_EPS)
             + __expf((x.z - m4) * INV_EPS) + __expf((x.w - m4) * INV_EPS);
    float Mn = fmaxf(M, m4);
    T = T * __expf((M - Mn) * INV_EPS) + t4 * __expf((m4 - Mn) * INV_EPS);
    M = Mn;
  }
#pragma unroll
  for (int o = 32; o; o >>= 1) {
    float M2 = __shfl_xor(M, o, 64);
    float T2 = __shfl_xor(T, o, 64);
    float Mn = fmaxf(M, M2);
    T = T * __expf((M - Mn) * INV_EPS) + T2 * __expf((M2 - Mn) * INV_EPS);
    M = Mn;
  }
  if (lane == 0) {
    (crop ? a.pmB : a.pmA)[row] = M;
    a.r[crop * Bn + row] = T;
    a.rinv[crop * Bn + row] = 1.0f / (T + TINYF);
  }
  const float thr = M - CUTF;

  int cnt = 0;
  for (int i = lane; i < KQ4; i += 64) {
    float4 x = rp[i];
    cnt += (x.x >= thr) + (x.y >= thr) + (x.z >= thr) + (x.w >= thr);
  }
  int incl = cnt;
#pragma unroll
  for (int o = 1; o < 64; o <<= 1) {
    int t = __shfl_up(incl, o, 64);
    if (lane >= o) incl += t;
  }
  int total = __shfl(incl, 63, 64);
  int p = incl - cnt;
  if (lane == 0) a.rowcnt[crop * Bn + row] = (unsigned)min(total, CAPR);

  float* crow = a.csrq + ((size_t)crop * Bn + row) * CAPR;
  unsigned short* cidx = a.csridx + ((size_t)crop * Bn + row) * CAPR;
  unsigned* ccnt = a.colcnt + crop * KP;
  float* cq_ = a.cscq + (size_t)crop * KP * CAPC;
  unsigned short* ci_ = a.cscidx + (size_t)crop * KP * CAPC;

  for (int i = lane; i < KQ4; i += 64) {
    float4 x = rp[i];
    int k0 = i * 4;
#define EMIT(val, kk)                                                          \
    if ((val) >= thr) {                                                        \
      float q = __expf(((val) - M) * INV_EPS);                                 \
      if (p < CAPR) { crow[p] = q; cidx[p] = (unsigned short)(kk); }           \
      unsigned slot = atomicAdd(&ccnt[kk], 1u);                                \
      if (slot < CAPC) {                                                       \
        size_t o2 = (size_t)(kk) * CAPC + slot;                                \
        cq_[o2] = q; ci_[o2] = (unsigned short)row;                            \
      }                                                                        \
      ++p;                                                                     \
    }
    EMIT(x.x, k0 + 0) EMIT(x.y, k0 + 1) EMIT(x.z, k0 + 2) EMIT(x.w, k0 + 3)
#undef EMIT
  }
}

// ---------------------------------------------------------------------------
// Iterate kernel (cooperative launch, custom fast barrier).
// ---------------------------------------------------------------------------
struct ItArgs {
  float* pAa; float* pCa; float* pAb; float* pCb;
  float* u; float* r; float* rinv; float* v; float* alpha;
  const unsigned* rowcnt; const unsigned* colcnt;
  const float* csrq; const unsigned short* csridx;
  const float* cscq; const unsigned short* cscidx;
  unsigned* errA; unsigned* errB;
  unsigned* bar;
};

__global__ __launch_bounds__(IT_THR) void sinkhorn_iterate(ItArgs a) {
  const int tid = threadIdx.x;
  const int lane = tid & 63;
  const int wv = blockIdx.x * (IT_THR / 64) + (tid >> 6);

  __shared__ float2 sred[16];
  __shared__ float serr[4];

  // hoist loop-invariant nnz counts into registers (compile-time indexed)
  int cN[MAXC], cCrop[MAXC];
#pragma unroll
  for (int s = 0; s < MAXC; ++s) {
    int vc = wv + s * IT_NWAVE;
    if (vc < 2 * Kn) {
      int crop = vc >= Kn;
      cCrop[s] = crop;
      cN[s] = min((int)a.colcnt[crop * KP + (vc - crop * Kn)], CAPC);
    } else { cCrop[s] = -1; cN[s] = 0; }
  }
  int rN[MAXR];
#pragma unroll
  for (int s = 0; s < MAXR; ++s) {
    int vr = wv + s * IT_NWAVE;
    rN[s] = min((int)a.rowcnt[vr], CAPR);
  }

  unsigned genl = 0;
  bool done0 = false, done1 = false;
  int it = 0;
  while (true) {
    ++it;
    // ---- col pass: v_k = tgt / (sum_b q * rinv_b + TINY)
    float cerr0 = 0.f, cerr1 = 0.f;
#pragma unroll
    for (int s = 0; s < MAXC; ++s) {
      int cc = cCrop[s];
      if (cc < 0) continue;
      if (cc ? done1 : done0) continue;
      int vc = wv + s * IT_NWAVE;
      int col = vc - cc * Kn;
      size_t base = ((size_t)cc * KP + col) * CAPC;
      const float* q = a.cscq + base;
      const unsigned short* ix = a.cscidx + base;
      const float* rb = a.rinv + cc * Bn;
      int n = cN[s];
      float acc = 0.f;
      for (int j = lane; j < n; j += 64) acc += q[j] * rb[ix[j]];
      acc = wsum(acc);
      float vk = TGTC / (acc + TINYF);
      if (lane == 0) a.v[cc * KP + col] = vk;
      float e = fabsf(vk * acc - TGTC);
      if (cc) cerr1 = fmaxf(cerr1, e); else cerr0 = fmaxf(cerr0, e);
    }
    if (it >= 3) {
      float2 bm = block_max2_16(cerr0, cerr1, sred);
      if (tid == 0) {
        if (!done0) atomicMax(&a.errA[2 * it + 1], __float_as_uint(bm.x));
        if (!done1) atomicMax(&a.errB[2 * it + 1], __float_as_uint(bm.y));
      }
    }
    gbar(a.bar, genl);
    // ---- row pass: r_new = Q @ v ; u = rinv_old ; rinv = 1/(r_new+TINY)
    float lerr0 = 0.f, lerr1 = 0.f;
#pragma unroll
    for (int s = 0; s < MAXR; ++s) {
      int vr = wv + s * IT_NWAVE;
      int crop = vr >= Bn;
      if (crop ? done1 : done0) continue;
      size_t base = (size_t)vr * CAPR;
      const float* q = a.csrq + base;
      const unsigned short* ix = a.csridx + base;
      const float* vb = a.v + crop * KP;
      int n = rN[s];
      float acc = 0.f;
      for (int j = lane; j < n; j += 64) acc += q[j] * vb[ix[j]];
      acc = wsum(acc);
      float uu = a.rinv[vr];
      if (lane == 0) {
        a.u[vr] = uu; a.r[vr] = acc;
        a.rinv[vr] = 1.0f / (acc + TINYF);
      }
      float e = fabsf(uu * acc - 1.0f);
      if (crop) lerr1 = fmaxf(lerr1, e); else lerr0 = fmaxf(lerr0, e);
    }
    if (it >= 3) {
      float2 bm = block_max2_16(lerr0, lerr1, sred);
      if (tid == 0) {
        if (!done0) atomicMax(&a.errA[2 * it], __float_as_uint(bm.x));
        if (!done1) atomicMax(&a.errB[2 * it], __float_as_uint(bm.y));
      }
    }
    gbar(a.bar, genl);
    // ---- per-crop convergence decision (uniform: same global values everywhere)
    if (it >= 3) {
      if (tid == 0) {
        serr[0] = __uint_as_float(__hip_atomic_load(&a.errA[2 * it], __ATOMIC_RELAXED, __HIP_MEMORY_SCOPE_AGENT));
        serr[1] = __uint_as_float(__hip_atomic_load(&a.errA[2 * it + 1], __ATOMIC_RELAXED, __HIP_MEMORY_SCOPE_AGENT));
        serr[2] = __uint_as_float(__hip_atomic_load(&a.errB[2 * it], __ATOMIC_RELAXED, __HIP_MEMORY_SCOPE_AGENT));
        serr[3] = __uint_as_float(__hip_atomic_load(&a.errB[2 * it + 1], __ATOMIC_RELAXED, __HIP_MEMORY_SCOPE_AGENT));
      }
      __syncthreads();
      if (!done0) done0 = (it >= 100) || (fmaxf(serr[0], serr[1]) <= TOLF);
      if (!done1) done1 = (it >= 100) || (fmaxf(serr[2], serr[3]) <= TOLF);
      __syncthreads();
      if (done0 && done1) break;
    }
  }

  // ---- final normalization: alpha, then C, then A (P = q * A_b * C_k)
  for (int g = blockIdx.x * IT_THR + tid; g < 2 * Bn; g += IT_NBLK * IT_THR) {
    float uu = a.u[g], rr = a.r[g];
    a.alpha[g] = uu / fmaxf(uu * rr, TINYF);
  }
  gbar(a.bar, genl);
#pragma unroll
  for (int s = 0; s < MAXC; ++s) {
    int cc = cCrop[s];
    if (cc < 0) continue;
    int vc = wv + s * IT_NWAVE;
    int col = vc - cc * Kn;
    size_t base = ((size_t)cc * KP + col) * CAPC;
    const float* q = a.cscq + base;
    const unsigned short* ix = a.cscidx + base;
    const float* al = a.alpha + cc * Bn;
    int n = cN[s];
    float d = 0.f;
    for (int j = lane; j < n; j += 64) d += q[j] * al[ix[j]];
    d = wsum(d);
    float vk = a.v[cc * KP + col];
    if (lane == 0)
      (cc ? a.pCb : a.pCa)[col] = vk * TGTC / fmaxf(vk * d, TINYF);
  }
  gbar(a.bar, genl);
#pragma unroll
  for (int s = 0; s < MAXR; ++s) {
    int vr = wv + s * IT_NWAVE;
    int crop = vr >= Bn;
    size_t base = (size_t)vr * CAPR;
    const float* q = a.csrq + base;
    const unsigned short* ix = a.csridx + base;
    const float* pc = crop ? a.pCb : a.pCa;
    int n = rN[s];
    float e = 0.f;
    for (int j = lane; j < n; j += 64) e += q[j] * pc[ix[j]];
    e = wsum(e);
    if (lane == 0) {
      float al = a.alpha[vr];
      (crop ? a.pAb : a.pAa)[vr - crop * Bn] = al / fmaxf(al * e, TINYF);
    }
  }
}

// ---------------------------------------------------------------------------
// Dense fallback (round-0 kernel), used only if ws_size is too small.
// ---------------------------------------------------------------------------
__global__ __launch_bounds__(256, 2) void sinkhorn_dense(
    Ptr8 ptrs, const int* __restrict__ idxp,
    float* __restrict__ ws_m, float* __restrict__ ws_u, float* __restrict__ ws_r,
    float* __restrict__ ws_A, float* __restrict__ ws_v, float* __restrict__ ws_C,
    float* __restrict__ cpart, unsigned* __restrict__ errbuf)
{
  cg::grid_group grid = cg::this_grid();
  const int idx = (*idxp) & 7;
  const float* __restrict__ lg = ptrs.p[idx];
  const int tid = threadIdx.x;
  const int lane = tid & 63;
  const int gw = blockIdx.x * 4 + (tid >> 6);
  const int stripe = blockIdx.x % NSTR;
  const int chunk = blockIdx.x / NSTR;
  const int kcol = stripe * 256 + tid;
  const int rs = (chunk * Bn) / NCH;
  const int re = ((chunk + 1) * Bn) / NCH;

  for (int row = gw; row < Bn; row += NW_S) {
    const float4* rp = (const float4*)(lg + (size_t)row * Kn);
    float M = -INFINITY, T = 0.f;
    for (int i = lane; i < KQ4; i += 64) {
      float4 x = rp[i];
      float m4 = fmaxf(fmaxf(x.x, x.y), fmaxf(x.z, x.w));
      float t4 = __expf((x.x - m4) * INV_EPS) + __expf((x.y - m4) * INV_EPS)
               + __expf((x.z - m4) * INV_EPS) + __expf((x.w - m4) * INV_EPS);
      float Mn = fmaxf(M, m4);
      T = T * __expf((M - Mn) * INV_EPS) + t4 * __expf((m4 - Mn) * INV_EPS);
      M = Mn;
    }
#pragma unroll
    for (int o = 32; o; o >>= 1) {
      float M2 = __shfl_xor(M, o, 64);
      float T2 = __shfl_xor(T, o, 64);
      float Mn = fmaxf(M, M2);
      T = T * __expf((M - Mn) * INV_EPS) + T2 * __expf((M2 - Mn) * INV_EPS);
      M = Mn;
    }
    if (lane == 0) { ws_m[row] = M; ws_r[row] = T; }
  }
  grid.sync(); __threadfence();

  int it = 0;
  while (true) {
    ++it;
    {
      float acc = 0.f;
      if (kcol < Kn) {
        for (int row = rs; row < re; ++row) {
          float u = 1.0f / (ws_r[row] + TINYF);
          acc += u * __expf((lg[(size_t)row * Kn + kcol] - ws_m[row]) * INV_EPS);
        }
      }
      cpart[chunk * KP + stripe * 256 + tid] = acc;
    }
    grid.sync(); __threadfence();
    {
      int k = blockIdx.x * 256 + tid;
      float cerr = 0.f;
      if (k < Kn) {
        float c = 0.f;
        for (int ch = 0; ch < NCH; ++ch) c += cpart[ch * KP + k];
        float vk = TGTC / (c + TINYF);
        ws_v[k] = vk;
        cerr = fabsf(vk * c - TGTC);
      }
      float bm = block_max(cerr);
      if (tid == 0) atomicMax(&errbuf[2 * it + 1], __float_as_uint(bm));
    }
    grid.sync(); __threadfence();
    {
      float lerr = 0.f;
      for (int row = gw; row < Bn; row += NW_S) {
        const float4* rp = (const float4*)(lg + (size_t)row * Kn);
        const float4* vp = (const float4*)ws_v;
        float mm = ws_m[row];
        float u = 1.0f / (ws_r[row] + TINYF);
        float Ssum = 0.f;
        for (int i = lane; i < KQ4; i += 64) {
          float4 x = rp[i];
          float4 vv = vp[i];
          Ssum += __expf((x.x - mm) * INV_EPS) * vv.x
                + __expf((x.y - mm) * INV_EPS) * vv.y
                + __expf((x.z - mm) * INV_EPS) * vv.z
                + __expf((x.w - mm) * INV_EPS) * vv.w;
        }
        Ssum = wsum(Ssum);
        if (lane == 0) { ws_u[row] = u; ws_r[row] = Ssum; }
        lerr = fmaxf(lerr, fabsf(u * Ssum - 1.0f));
      }
      float bm = block_max(lerr);
      if (tid == 0) atomicMax(&errbuf[2 * it], __float_as_uint(bm));
    }
    grid.sync(); __threadfence();
    unsigned rbits = __hip_atomic_load(&errbuf[2 * it], __ATOMIC_RELAXED, __HIP_MEMORY_SCOPE_AGENT);
    unsigned cbits = __hip_atomic_load(&errbuf[2 * it + 1], __ATOMIC_RELAXED, __HIP_MEMORY_SCOPE_AGENT);
    float err = fmaxf(__uint_as_float(rbits), __uint_as_float(cbits));
    if (it >= 3 && (it >= 100 || err <= TOLF)) break;
  }

  {
    float acc = 0.f;
    if (kcol < Kn) {
      for (int row = rs; row < re; ++row) {
        float u = ws_u[row];
        float sp = fmaxf(u * ws_r[row], TINYF);
        acc += (u / sp) * __expf((lg[(size_t)row * Kn + kcol] - ws_m[row]) * INV_EPS);
      }
    }
    cpart[chunk * KP + stripe * 256 + tid] = acc;
  }
  grid.sync(); __threadfence();
  {
    int k = blockIdx.x * 256 + tid;
    if (k < Kn) {
      float d = 0.f;
      for (int ch = 0; ch < NCH; ++ch) d += cpart[ch * KP + k];
      float vk = ws_v[k];
      ws_C[k] = vk * TGTC / fmaxf(vk * d, TINYF);
    }
  }
  grid.sync(); __threadfence();
  {
    for (int row = gw; row < Bn; row += NW_S) {
      const float4* rp = (const float4*)(lg + (size_t)row * Kn);
      const float4* cp = (const float4*)ws_C;
      float mm = ws_m[row];
      float e = 0.f;
      for (int i = lane; i < KQ4; i += 64) {
        float4 x = rp[i];
        float4 cc = cp[i];
        e += __expf((x.x - mm) * INV_EPS) * cc.x
           + __expf((x.y - mm) * INV_EPS) * cc.y
           + __expf((x.z - mm) * INV_EPS) * cc.z
           + __expf((x.w - mm) * INV_EPS) * cc.w;
      }
      e = wsum(e);
      if (lane == 0) {
        float u = ws_u[row];
        float sp = fmaxf(u * ws_r[row], TINYF);
        float us = u / sp;
        float w = us * e;
        ws_A[row] = us / fmaxf(w, TINYF);
      }
    }
  }
}

// ---------------------------------------------------------------------------
// Fused loss/entropy/qmax pass (persist layout: m@0, A@4096, C@8192)
// ---------------------------------------------------------------------------
__global__ __launch_bounds__(256) void loss_kernel(
    Ptr8 ptrs, const int* __restrict__ iap, const int* __restrict__ ibp,
    const float* __restrict__ wsa, const float* __restrict__ wsb,
    float* __restrict__ out)
{
  const int ia = (*iap) & 7;
  const int ib = (*ibp) & 7;
  const int lane = threadIdx.x & 63;
  const int row = blockIdx.x * 4 + (threadIdx.x >> 6);

  const float ma = wsa[row];
  const float Aa = wsa[4096 + row];
  const float mb = wsb[row];
  const float Ab = wsb[4096 + row];
  const float4* Ca4 = (const float4*)(wsa + 8192);
  const float4* Cb4 = (const float4*)(wsb + 8192);
  size_t off = (size_t)row * Kn;
  const float4* X4[8];
#pragma unroll
  for (int c = 0; c < 8; ++c) X4[c] = (const float4*)(ptrs.p[c] + off);
  const float4* xa4 = (const float4*)(ptrs.p[ia] + off);
  const float4* xb4 = (const float4*)(ptrs.p[ib] + off);

  float M[8], S[8], da[8], db[8];
#pragma unroll
  for (int c = 0; c < 8; ++c) { M[c] = -INFINITY; S[c] = 0.f; da[c] = 0.f; db[c] = 0.f; }
  float enta = 0.f, entb = 0.f, ra = 0.f, rb = 0.f, qam = 0.f, qbm = 0.f;

  for (int i = lane; i < KQ4; i += 64) {
    float4 xa = xa4[i], xb = xb4[i];
    float4 ca = Ca4[i], cb = Cb4[i];
    float qa0 = __expf((xa.x - ma) * INV_EPS) * Aa * ca.x;
    float qa1 = __expf((xa.y - ma) * INV_EPS) * Aa * ca.y;
    float qa2 = __expf((xa.z - ma) * INV_EPS) * Aa * ca.z;
    float qa3 = __expf((xa.w - ma) * INV_EPS) * Aa * ca.w;
    float qb0 = __expf((xb.x - mb) * INV_EPS) * Ab * cb.x;
    float qb1 = __expf((xb.y - mb) * INV_EPS) * Ab * cb.y;
    float qb2 = __expf((xb.z - mb) * INV_EPS) * Ab * cb.z;
    float qb3 = __expf((xb.w - mb) * INV_EPS) * Ab * cb.w;
    ra += (qa0 + qa1) + (qa2 + qa3);
    rb += (qb0 + qb1) + (qb2 + qb3);
    enta += qa0 * __logf(qa0 + TINYF) + qa1 * __logf(qa1 + TINYF)
          + qa2 * __logf(qa2 + TINYF) + qa3 * __logf(qa3 + TINYF);
    entb += qb0 * __logf(qb0 + TINYF) + qb1 * __logf(qb1 + TINYF)
          + qb2 * __logf(qb2 + TINYF) + qb3 * __logf(qb3 + TINYF);
    qam = fmaxf(qam, fmaxf(fmaxf(qa0, qa1), fmaxf(qa2, qa3)));
    qbm = fmaxf(qbm, fmaxf(fmaxf(qb0, qb1), fmaxf(qb2, qb3)));
#pragma unroll
    for (int c = 0; c < 8; ++c) {
      float4 x = X4[c][i];
      float y0 = x.x * INV_TEMP, y1 = x.y * INV_TEMP;
      float y2 = x.z * INV_TEMP, y3 = x.w * INV_TEMP;
      float m4 = fmaxf(fmaxf(y0, y1), fmaxf(y2, y3));
      float t4 = __expf(y0 - m4) + __expf(y1 - m4) + __expf(y2 - m4) + __expf(y3 - m4);
      float Mn = fmaxf(M[c], m4);
      S[c] = S[c] * __expf(M[c] - Mn) + t4 * __expf(m4 - Mn);
      M[c] = Mn;
      da[c] += qa0 * x.x + qa1 * x.y + qa2 * x.z + qa3 * x.w;
      db[c] += qb0 * x.x + qb1 * x.y + qb2 * x.z + qb3 * x.w;
    }
  }

#pragma unroll
  for (int c = 0; c < 8; ++c) {
#pragma unroll
    for (int o = 32; o; o >>= 1) {
      float M2 = __shfl_xor(M[c], o, 64);
      float S2 = __shfl_xor(S[c], o, 64);
      float Mn = fmaxf(M[c], M2);
      S[c] = S[c] * __expf(M[c] - Mn) + S2 * __expf(M2 - Mn);
      M[c] = Mn;
    }
    da[c] = wsum(da[c]);
    db[c] = wsum(db[c]);
  }
  enta = wsum(enta); entb = wsum(entb);
  ra = wsum(ra); rb = wsum(rb);
  qam = wmax(qam); qbm = wmax(qbm);

  if (lane == 0) {
    float lsum = 0.f;
    int nt = 0;
#pragma unroll
    for (int c = 0; c < 8; ++c) {
      float L = M[c] + __logf(S[c]);
      if (c != ia) { lsum -= INV_TEMP * da[c] - L * ra; ++nt; }
      if (c != ib) { lsum -= INV_TEMP * db[c] - L * rb; ++nt; }
    }
    atomicAdd(&out[0], lsum / ((float)nt * (float)Bn));
    atomicAdd(&out[1], -0.5f / (float)Bn * (enta + entb));
    atomicAdd(&out[2], 0.5f / (float)Bn * (qam + qbm));
  }
}

// ---------------------------------------------------------------------------
extern "C" void kernel_launch(void* const* d_in, const int* in_sizes, int n_in,
                              void* d_out, int out_size, void* d_ws, size_t ws_size,
                              hipStream_t stream)
{
  (void)in_sizes; (void)n_in; (void)out_size;
  Ptr8 ptrs;
  for (int c = 0; c < 8; ++c) ptrs.p[c] = (const float*)d_in[c];
  const int* iap = (const int*)d_in[8];
  const int* ibp = (const int*)d_in[9];
  float* ws = (float*)d_ws;
  float* out = (float*)d_out;

  // float-offset layout (two-crop concurrent)
  float* PA = ws;                         // m,A,C persist crop a (11264)
  float* PB = ws + 11264;                 // persist crop b -> 22528
  float* u_ = ws + 22528;                 // [2*Bn] -> 30720
  float* r_ = ws + 30720;                 // [2*Bn] -> 38912
  float* ri_ = ws + 38912;                // [2*Bn] rinv -> 47104
  float* v_ = ws + 47104;                 // [2*KP] -> 53248
  float* al = ws + 53248;                 // [2*Bn] -> 61440
  unsigned* rowcnt = (unsigned*)(ws + 61440);   // [2*Bn] -> 69632
  unsigned* colcnt = (unsigned*)(ws + 69632);   // [2*KP] -> 75776
  unsigned* errA = (unsigned*)(ws + 75776);     // 512 -> 76288
  unsigned* errB = (unsigned*)(ws + 76288);     // 512 -> 76800
  unsigned* bar = (unsigned*)(ws + 76800);      // 64  -> 76864
  float* csrq = ws + 76864;                               // 2*4096*448
  unsigned short* csridx = (unsigned short*)(ws + 3746880);   // u16
  float* cscq = ws + 5581888;                             // 2*3072*448
  unsigned short* cscidx = (unsigned short*)(ws + 8334400);   // u16
  const size_t need_bytes = (size_t)9710656 * 4;          // ~38.8 MB

  // zero colcnt + err + bar (contiguous from colcnt: 6144+512+512+64 uints)
  hipMemsetAsync(colcnt, 0, 7232 * sizeof(unsigned), stream);
  hipMemsetAsync(d_out, 0, 3 * sizeof(float), stream);

  if (ws_size >= need_bytes) {
    BuildArgs ba;
    ba.ptrs = ptrs; ba.iap = iap; ba.ibp = ibp;
    ba.pmA = PA; ba.pmB = PB;
    ba.r = r_; ba.rinv = ri_;
    ba.rowcnt = rowcnt; ba.colcnt = colcnt;
    ba.csrq = csrq; ba.csridx = csridx; ba.cscq = cscq; ba.cscidx = cscidx;
    hipLaunchKernelGGL(build_sparse, dim3(BLD_NBLK), dim3(256), 0, stream, ba);

    ItArgs ia;
    ia.pAa = PA + 4096; ia.pCa = PA + 8192;
    ia.pAb = PB + 4096; ia.pCb = PB + 8192;
    ia.u = u_; ia.r = r_; ia.rinv = ri_; ia.v = v_; ia.alpha = al;
    ia.rowcnt = rowcnt; ia.colcnt = colcnt;
    ia.csrq = csrq; ia.csridx = csridx; ia.cscq = cscq; ia.cscidx = cscidx;
    ia.errA = errA; ia.errB = errB; ia.bar = bar;
    void* args1[] = { (void*)&ia };
    hipLaunchCooperativeKernel((const void*)sinkhorn_iterate, dim3(IT_NBLK), dim3(IT_THR),
                               (void**)args1, 0u, stream);
  } else {
    // dense fallback (round-0 path); cpart reuses the csrq region start
    float* cpart = ws + 76864;   // NCH*KP = 122880 floats
    {
      float* m = PA; float* A = PA + 4096; float* C = PA + 8192;
      void* args[] = { (void*)&ptrs, (void*)&iap, (void*)&m, (void*)&u_, (void*)&r_,
                       (void*)&A, (void*)&v_, (void*)&C, (void*)&cpart, (void*)&errA };
      hipLaunchCooperativeKernel((const void*)sinkhorn_dense, dim3(GRID_S), dim3(256),
                                 (void**)args, 0u, stream);
    }
    {
      float* m = PB; float* A = PB + 4096; float* C = PB + 8192;
      void* args[] = { (void*)&ptrs, (void*)&ibp, (void*)&m, (void*)&u_, (void*)&r_,
                       (void*)&A, (void*)&v_, (void*)&C, (void*)&cpart, (void*)&errB };
      hipLaunchCooperativeKernel((const void*)sinkhorn_dense, dim3(GRID_S), dim3(256),
                                 (void**)args, 0u, stream);
    }
  }

  loss_kernel<<<dim3(Bn / 4), dim3(256), 0, stream>>>(ptrs, iap, ibp, PA, PB, out);
}

// Round 3
// 3787.960 us; speedup vs baseline: 10.8181x; 1.2476x over previous
//
#include <hip/hip_runtime.h>
#include <hip/hip_cooperative_groups.h>
#include <math.h>

namespace cg = cooperative_groups;

struct Ptr8 { const float* p[8]; };

#define Bn 4096
#define Kn 3000
#define KQ4 750
#define KP 3072
#define INV_EPS 20.0f
#define INV_TEMP 10.0f
#define TINYF 1e-12f
#define TOLF 1e-3f
#define TGTC (4096.0f/3000.0f)

// sparse config: keep s >= rowmax - CUTF  (q >= e^-28 ~ 7e-13)
#define CAPR 448
#define CAPC 448
#define CUTF 1.4f

// build kernel: one wave per (crop,row) -> 2*4096 waves = 2048 blocks
#define BLD_NBLK 2048

// iterate kernel: 64 blocks x 1024 threads, LLC-coherent exchange + LDS staging
#define IT_NBLK 64
#define IT_THR 1024
#define IT_NWAVE (IT_NBLK * IT_THR / 64)    // 1024
#define MAXC 6                               // ceil(2*Kn / IT_NWAVE)
#define MAXR 8                               // 2*Bn / IT_NWAVE
#define BARSTRIDE 32                         // uints between arrive flags (128B)

// LLC-coherent (cache-bypassing) access for cross-block exchanged data.
// No fences anywhere in the loop -> read-only CSR/CSC stays L2-resident.
#define ALD(p)    __hip_atomic_load((p), __ATOMIC_RELAXED, __HIP_MEMORY_SCOPE_AGENT)
#define AST(p, x) __hip_atomic_store((p), (x), __ATOMIC_RELAXED, __HIP_MEMORY_SCOPE_AGENT)

// dense fallback config (round-0)
#define NSTR 12
#define NCH 40
#define GRID_S 480
#define NW_S (GRID_S * 4)

__device__ __forceinline__ float wsum(float x) {
#pragma unroll
  for (int o = 32; o; o >>= 1) x += __shfl_xor(x, o, 64);
  return x;
}
__device__ __forceinline__ float wmax(float x) {
#pragma unroll
  for (int o = 32; o; o >>= 1) x = fmaxf(x, __shfl_xor(x, o, 64));
  return x;
}
// 4-wave block max (256-thread kernels)
__device__ __forceinline__ float block_max(float x) {
  __shared__ float s[4];
  x = wmax(x);
  if ((threadIdx.x & 63) == 0) s[threadIdx.x >> 6] = x;
  __syncthreads();
  float r = fmaxf(fmaxf(s[0], s[1]), fmaxf(s[2], s[3]));
  __syncthreads();
  return r;
}

// ---------------------------------------------------------------------------
// Build kernel (non-cooperative): per (crop,row) wave computes row max m,
// r0 = sum exp((s-m)*INV_EPS), then CSR+CSC of q for s >= m - CUTF.
// ---------------------------------------------------------------------------
struct BuildArgs {
  Ptr8 ptrs;
  const int* iap; const int* ibp;
  float* pmA; float* pmB;
  float* r;                          // [2*Bn]
  unsigned* rowcnt;                  // [2*Bn]
  unsigned* colcnt;                  // [2*KP], pre-zeroed
  float* csrq; unsigned short* csridx;
  float* cscq; unsigned short* cscidx;
};

__global__ __launch_bounds__(256, 2) void build_sparse(BuildArgs a) {
  const int tid = threadIdx.x;
  const int lane = tid & 63;
  const int wv = blockIdx.x * 4 + (tid >> 6);
  const int crop = wv >> 12;
  const int row = wv & (Bn - 1);
  const int idx = ((crop ? *a.ibp : *a.iap) & 7);
  const float* __restrict__ lg = a.ptrs.p[idx];
  const float4* rp = (const float4*)(lg + (size_t)row * Kn);

  float M = -INFINITY, T = 0.f;
  for (int i = lane; i < KQ4; i += 64) {
    float4 x = rp[i];
    float m4 = fmaxf(fmaxf(x.x, x.y), fmaxf(x.z, x.w));
    float t4 = __expf((x.x - m4) * INV_EPS) + __expf((x.y - m4) * INV_EPS)
             + __expf((x.z - m4) * INV_EPS) + __expf((x.w - m4) * INV_EPS);
    float Mn = fmaxf(M, m4);
    T = T * __expf((M - Mn) * INV_EPS) + t4 * __expf((m4 - Mn) * INV_EPS);
    M = Mn;
  }
#pragma unroll
  for (int o = 32; o; o >>= 1) {
    float M2 = __shfl_xor(M, o, 64);
    float T2 = __shfl_xor(T, o, 64);
    float Mn = fmaxf(M, M2);
    T = T * __expf((M - Mn) * INV_EPS) + T2 * __expf((M2 - Mn) * INV_EPS);
    M = Mn;
  }
  if (lane == 0) {
    (crop ? a.pmB : a.pmA)[row] = M;
    a.r[crop * Bn + row] = T;
  }
  const float thr = M - CUTF;

  int cnt = 0;
  for (int i = lane; i < KQ4; i += 64) {
    float4 x = rp[i];
    cnt += (x.x >= thr) + (x.y >= thr) + (x.z >= thr) + (x.w >= thr);
  }
  int incl = cnt;
#pragma unroll
  for (int o = 1; o < 64; o <<= 1) {
    int t = __shfl_up(incl, o, 64);
    if (lane >= o) incl += t;
  }
  int total = __shfl(incl, 63, 64);
  int p = incl - cnt;
  if (lane == 0) a.rowcnt[crop * Bn + row] = (unsigned)min(total, CAPR);

  float* crow = a.csrq + ((size_t)crop * Bn + row) * CAPR;
  unsigned short* cidx = a.csridx + ((size_t)crop * Bn + row) * CAPR;
  unsigned* ccnt = a.colcnt + crop * KP;
  float* cq_ = a.cscq + (size_t)crop * KP * CAPC;
  unsigned short* ci_ = a.cscidx + (size_t)crop * KP * CAPC;

  for (int i = lane; i < KQ4; i += 64) {
    float4 x = rp[i];
    int k0 = i * 4;
#define EMIT(val, kk)                                                          \
    if ((val) >= thr) {                                                        \
      float q = __expf(((val) - M) * INV_EPS);                                 \
      if (p < CAPR) { crow[p] = q; cidx[p] = (unsigned short)(kk); }           \
      unsigned slot = atomicAdd(&ccnt[kk], 1u);                                \
      if (slot < CAPC) {                                                       \
        size_t o2 = (size_t)(kk) * CAPC + slot;                                \
        cq_[o2] = q; ci_[o2] = (unsigned short)row;                            \
      }                                                                        \
      ++p;                                                                     \
    }
    EMIT(x.x, k0 + 0) EMIT(x.y, k0 + 1) EMIT(x.z, k0 + 2) EMIT(x.w, k0 + 3)
#undef EMIT
  }
}

// ---------------------------------------------------------------------------
// Iterate kernel: fence-free. Cross-block data via LLC atomics; gathered
// vectors staged to LDS; flag-vector barrier (no same-address contention).
// ---------------------------------------------------------------------------
struct ItArgs {
  float* pAa; float* pCa; float* pAb; float* pCb;
  float* u; float* r; float* v;       // [2*Bn],[2*Bn],[2*KP]  (LLC-coherent)
  const unsigned* rowcnt; const unsigned* colcnt;
  const float* csrq; const unsigned short* csridx;
  const float* cscq; const unsigned short* cscidx;
  unsigned* err;                      // [2 parity][4][64]
  unsigned* arrive;                   // [64 * BARSTRIDE]
  unsigned* release;                  // [1]
};

__device__ __forceinline__ void gbar2(unsigned* arrive, unsigned* release, unsigned g) {
  __syncthreads();   // drains each wave's stores (vmcnt 0) before arrival
  if (threadIdx.x == 0)
    AST(&arrive[blockIdx.x * BARSTRIDE], g);
  if (blockIdx.x == 0) {
    if (threadIdx.x < 64) {
      while ((int)(ALD(&arrive[threadIdx.x * BARSTRIDE]) - g) < 0)
        __builtin_amdgcn_s_sleep(1);
    }
    __syncthreads();
    if (threadIdx.x == 0) AST(release, g);
  } else {
    if (threadIdx.x == 0) {
      while ((int)(ALD(release) - g) < 0)
        __builtin_amdgcn_s_sleep(1);
    }
  }
  __syncthreads();
}

__global__ __launch_bounds__(IT_THR) void sinkhorn_iterate(ItArgs a) {
  const int tid = threadIdx.x;
  const int lane = tid & 63;
  const int bid = blockIdx.x;
  const int wv = bid * (IT_THR / 64) + (tid >> 6);

  __shared__ float lds_rinv[2 * Bn];   // 32 KB: rinv (loop) / alpha (epilogue)
  __shared__ float lds_v[2 * KP];      // 24 KB: v (loop) / pC (epilogue)
  __shared__ float2 sred[16];
  __shared__ float serr[2];

  // hoist loop-invariant nnz counts into registers (compile-time indexed)
  int cN[MAXC], cCrop[MAXC];
#pragma unroll
  for (int s = 0; s < MAXC; ++s) {
    int vc = wv + s * IT_NWAVE;
    if (vc < 2 * Kn) {
      int crop = vc >= Kn;
      cCrop[s] = crop;
      cN[s] = min((int)a.colcnt[crop * KP + (vc - crop * Kn)], CAPC);
    } else { cCrop[s] = -1; cN[s] = 0; }
  }
  int rN[MAXR];
#pragma unroll
  for (int s = 0; s < MAXR; ++s) {
    int vr = wv + s * IT_NWAVE;
    rN[s] = min((int)a.rowcnt[vr], CAPR);
  }

  unsigned gen = 0;
  bool done0 = false, done1 = false;
  int it = 0;
  while (true) {
    ++it;
    const int par = it & 1;
    // ---- stage rinv = 1/(r+TINY) into LDS (coalesced LLC loads)
    for (int g = tid; g < 2 * Bn; g += IT_THR) {
      int cr = g >> 12;
      if (!(cr ? done1 : done0))
        lds_rinv[g] = 1.0f / (ALD(&a.r[g]) + TINYF);
    }
    __syncthreads();
    // ---- col pass: v_k = tgt / (sum_b q * rinv_b + TINY)
    float cerr0 = 0.f, cerr1 = 0.f;
#pragma unroll
    for (int s = 0; s < MAXC; ++s) {
      int cc = cCrop[s];
      if (cc < 0) continue;
      if (cc ? done1 : done0) continue;
      int vc = wv + s * IT_NWAVE;
      int col = vc - cc * Kn;
      size_t base = ((size_t)cc * KP + col) * CAPC;
      const float* q = a.cscq + base;
      const unsigned short* ix = a.cscidx + base;
      int n = cN[s];
      float acc = 0.f;
      for (int j = lane; j < n; j += 64) acc += q[j] * lds_rinv[cc * Bn + ix[j]];
      acc = wsum(acc);
      float vk = TGTC / (acc + TINYF);
      if (lane == 0) AST(&a.v[cc * KP + col], vk);
      float e = fabsf(vk * acc - TGTC);
      if (cc) cerr1 = fmaxf(cerr1, e); else cerr0 = fmaxf(cerr0, e);
    }
    if (it >= 3) {
      cerr0 = wmax(cerr0); cerr1 = wmax(cerr1);
      if (lane == 0) sred[tid >> 6] = make_float2(cerr0, cerr1);
      __syncthreads();
      if (tid == 0) {
        float m0 = sred[0].x, m1 = sred[0].y;
#pragma unroll
        for (int i = 1; i < 16; ++i) { m0 = fmaxf(m0, sred[i].x); m1 = fmaxf(m1, sred[i].y); }
        if (!done0) AST(&a.err[par * 256 + 64 + bid], __float_as_uint(m0));
        if (!done1) AST(&a.err[par * 256 + 192 + bid], __float_as_uint(m1));
      }
    }
    gbar2(a.arrive, a.release, ++gen);
    // ---- stage v into LDS
    for (int g = tid; g < 2 * KP; g += IT_THR) {
      int cr = g >= KP;
      if (!(cr ? done1 : done0))
        lds_v[g] = ALD(&a.v[g]);
    }
    __syncthreads();
    // ---- row pass: r_new = Q @ v ; u = 1/(r_old+TINY) from LDS
    float lerr0 = 0.f, lerr1 = 0.f;
#pragma unroll
    for (int s = 0; s < MAXR; ++s) {
      int vr = wv + s * IT_NWAVE;
      int crop = vr >= Bn;
      if (crop ? done1 : done0) continue;
      size_t base = (size_t)vr * CAPR;
      const float* q = a.csrq + base;
      const unsigned short* ix = a.csridx + base;
      int n = rN[s];
      float acc = 0.f;
      for (int j = lane; j < n; j += 64) acc += q[j] * lds_v[crop * KP + ix[j]];
      acc = wsum(acc);
      float uu = lds_rinv[vr];
      if (lane == 0) {
        AST(&a.u[vr], uu);
        AST(&a.r[vr], acc);
      }
      float e = fabsf(uu * acc - 1.0f);
      if (crop) lerr1 = fmaxf(lerr1, e); else lerr0 = fmaxf(lerr0, e);
    }
    if (it >= 3) {
      lerr0 = wmax(lerr0); lerr1 = wmax(lerr1);
      if (lane == 0) sred[tid >> 6] = make_float2(lerr0, lerr1);
      __syncthreads();
      if (tid == 0) {
        float m0 = sred[0].x, m1 = sred[0].y;
#pragma unroll
        for (int i = 1; i < 16; ++i) { m0 = fmaxf(m0, sred[i].x); m1 = fmaxf(m1, sred[i].y); }
        if (!done0) AST(&a.err[par * 256 + bid], __float_as_uint(m0));
        if (!done1) AST(&a.err[par * 256 + 128 + bid], __float_as_uint(m1));
      }
    }
    gbar2(a.arrive, a.release, ++gen);
    // ---- convergence check: wave 0 reduces the 4x64 per-block err slots
    if (it >= 3) {
      if (tid < 64) {
        float e0 = __uint_as_float(ALD(&a.err[par * 256 + tid]));
        float e1 = __uint_as_float(ALD(&a.err[par * 256 + 64 + tid]));
        float e2 = __uint_as_float(ALD(&a.err[par * 256 + 128 + tid]));
        float e3 = __uint_as_float(ALD(&a.err[par * 256 + 192 + tid]));
        float eA = wmax(fmaxf(e0, e1));
        float eB = wmax(fmaxf(e2, e3));
        if (tid == 0) { serr[0] = eA; serr[1] = eB; }
      }
      __syncthreads();
      if (!done0) done0 = (it >= 100) || (serr[0] <= TOLF);
      if (!done1) done1 = (it >= 100) || (serr[1] <= TOLF);
      __syncthreads();
      if (done0 && done1) break;
    }
  }

  // ---- epilogue. u,r final & LLC-visible (post-barrier). lds_v holds final v.
  // alpha = u / max(u*r, TINY) computed redundantly per block into LDS.
  for (int g = tid; g < 2 * Bn; g += IT_THR) {
    float uu = ALD(&a.u[g]);
    float rr = ALD(&a.r[g]);
    lds_rinv[g] = uu / fmaxf(uu * rr, TINYF);
  }
  __syncthreads();
  // C_k = v*tgt / max(v*d, TINY), d = sum_b q*alpha
#pragma unroll
  for (int s = 0; s < MAXC; ++s) {
    int cc = cCrop[s];
    if (cc < 0) continue;
    int vc = wv + s * IT_NWAVE;
    int col = vc - cc * Kn;
    size_t base = ((size_t)cc * KP + col) * CAPC;
    const float* q = a.cscq + base;
    const unsigned short* ix = a.cscidx + base;
    int n = cN[s];
    float d = 0.f;
    for (int j = lane; j < n; j += 64) d += q[j] * lds_rinv[cc * Bn + ix[j]];
    d = wsum(d);
    float vk = lds_v[cc * KP + col];
    if (lane == 0)
      AST(&(cc ? a.pCb : a.pCa)[col], vk * TGTC / fmaxf(vk * d, TINYF));
  }
  gbar2(a.arrive, a.release, ++gen);
  // stage C into LDS, then A_b = alpha / max(alpha*e, TINY)
  for (int g = tid; g < 2 * KP; g += IT_THR) {
    int cr = g >= KP;
    lds_v[g] = ALD(&(cr ? a.pCb : a.pCa)[g - cr * KP]);
  }
  __syncthreads();
#pragma unroll
  for (int s = 0; s < MAXR; ++s) {
    int vr = wv + s * IT_NWAVE;
    int crop = vr >= Bn;
    size_t base = (size_t)vr * CAPR;
    const float* q = a.csrq + base;
    const unsigned short* ix = a.csridx + base;
    int n = rN[s];
    float e = 0.f;
    for (int j = lane; j < n; j += 64) e += q[j] * lds_v[crop * KP + ix[j]];
    e = wsum(e);
    if (lane == 0) {
      float al = lds_rinv[vr];
      (crop ? a.pAb : a.pAa)[vr - crop * Bn] = al / fmaxf(al * e, TINYF);
    }
  }
}

// ---------------------------------------------------------------------------
// Dense fallback (round-0 kernel), used only if ws_size is too small.
// ---------------------------------------------------------------------------
__global__ __launch_bounds__(256, 2) void sinkhorn_dense(
    Ptr8 ptrs, const int* __restrict__ idxp,
    float* __restrict__ ws_m, float* __restrict__ ws_u, float* __restrict__ ws_r,
    float* __restrict__ ws_A, float* __restrict__ ws_v, float* __restrict__ ws_C,
    float* __restrict__ cpart, unsigned* __restrict__ errbuf)
{
  cg::grid_group grid = cg::this_grid();
  const int idx = (*idxp) & 7;
  const float* __restrict__ lg = ptrs.p[idx];
  const int tid = threadIdx.x;
  const int lane = tid & 63;
  const int gw = blockIdx.x * 4 + (tid >> 6);
  const int stripe = blockIdx.x % NSTR;
  const int chunk = blockIdx.x / NSTR;
  const int kcol = stripe * 256 + tid;
  const int rs = (chunk * Bn) / NCH;
  const int re = ((chunk + 1) * Bn) / NCH;

  for (int row = gw; row < Bn; row += NW_S) {
    const float4* rp = (const float4*)(lg + (size_t)row * Kn);
    float M = -INFINITY, T = 0.f;
    for (int i = lane; i < KQ4; i += 64) {
      float4 x = rp[i];
      float m4 = fmaxf(fmaxf(x.x, x.y), fmaxf(x.z, x.w));
      float t4 = __expf((x.x - m4) * INV_EPS) + __expf((x.y - m4) * INV_EPS)
               + __expf((x.z - m4) * INV_EPS) + __expf((x.w - m4) * INV_EPS);
      float Mn = fmaxf(M, m4);
      T = T * __expf((M - Mn) * INV_EPS) + t4 * __expf((m4 - Mn) * INV_EPS);
      M = Mn;
    }
#pragma unroll
    for (int o = 32; o; o >>= 1) {
      float M2 = __shfl_xor(M, o, 64);
      float T2 = __shfl_xor(T, o, 64);
      float Mn = fmaxf(M, M2);
      T = T * __expf((M - Mn) * INV_EPS) + T2 * __expf((M2 - Mn) * INV_EPS);
      M = Mn;
    }
    if (lane == 0) { ws_m[row] = M; ws_r[row] = T; }
  }
  grid.sync(); __threadfence();

  int it = 0;
  while (true) {
    ++it;
    {
      float acc = 0.f;
      if (kcol < Kn) {
        for (int row = rs; row < re; ++row) {
          float u = 1.0f / (ws_r[row] + TINYF);
          acc += u * __expf((lg[(size_t)row * Kn + kcol] - ws_m[row]) * INV_EPS);
        }
      }
      cpart[chunk * KP + stripe * 256 + tid] = acc;
    }
    grid.sync(); __threadfence();
    {
      int k = blockIdx.x * 256 + tid;
      float cerr = 0.f;
      if (k < Kn) {
        float c = 0.f;
        for (int ch = 0; ch < NCH; ++ch) c += cpart[ch * KP + k];
        float vk = TGTC / (c + TINYF);
        ws_v[k] = vk;
        cerr = fabsf(vk * c - TGTC);
      }
      float bm = block_max(cerr);
      if (tid == 0) atomicMax(&errbuf[2 * it + 1], __float_as_uint(bm));
    }
    grid.sync(); __threadfence();
    {
      float lerr = 0.f;
      for (int row = gw; row < Bn; row += NW_S) {
        const float4* rp = (const float4*)(lg + (size_t)row * Kn);
        const float4* vp = (const float4*)ws_v;
        float mm = ws_m[row];
        float u = 1.0f / (ws_r[row] + TINYF);
        float Ssum = 0.f;
        for (int i = lane; i < KQ4; i += 64) {
          float4 x = rp[i];
          float4 vv = vp[i];
          Ssum += __expf((x.x - mm) * INV_EPS) * vv.x
                + __expf((x.y - mm) * INV_EPS) * vv.y
                + __expf((x.z - mm) * INV_EPS) * vv.z
                + __expf((x.w - mm) * INV_EPS) * vv.w;
        }
        Ssum = wsum(Ssum);
        if (lane == 0) { ws_u[row] = u; ws_r[row] = Ssum; }
        lerr = fmaxf(lerr, fabsf(u * Ssum - 1.0f));
      }
      float bm = block_max(lerr);
      if (tid == 0) atomicMax(&errbuf[2 * it], __float_as_uint(bm));
    }
    grid.sync(); __threadfence();
    unsigned rbits = __hip_atomic_load(&errbuf[2 * it], __ATOMIC_RELAXED, __HIP_MEMORY_SCOPE_AGENT);
    unsigned cbits = __hip_atomic_load(&errbuf[2 * it + 1], __ATOMIC_RELAXED, __HIP_MEMORY_SCOPE_AGENT);
    float err = fmaxf(__uint_as_float(rbits), __uint_as_float(cbits));
    if (it >= 3 && (it >= 100 || err <= TOLF)) break;
  }

  {
    float acc = 0.f;
    if (kcol < Kn) {
      for (int row = rs; row < re; ++row) {
        float u = ws_u[row];
        float sp = fmaxf(u * ws_r[row], TINYF);
        acc += (u / sp) * __expf((lg[(size_t)row * Kn + kcol] - ws_m[row]) * INV_EPS);
      }
    }
    cpart[chunk * KP + stripe * 256 + tid] = acc;
  }
  grid.sync(); __threadfence();
  {
    int k = blockIdx.x * 256 + tid;
    if (k < Kn) {
      float d = 0.f;
      for (int ch = 0; ch < NCH; ++ch) d += cpart[ch * KP + k];
      float vk = ws_v[k];
      ws_C[k] = vk * TGTC / fmaxf(vk * d, TINYF);
    }
  }
  grid.sync(); __threadfence();
  {
    for (int row = gw; row < Bn; row += NW_S) {
      const float4* rp = (const float4*)(lg + (size_t)row * Kn);
      const float4* cp = (const float4*)ws_C;
      float mm = ws_m[row];
      float e = 0.f;
      for (int i = lane; i < KQ4; i += 64) {
        float4 x = rp[i];
        float4 cc = cp[i];
        e += __expf((x.x - mm) * INV_EPS) * cc.x
           + __expf((x.y - mm) * INV_EPS) * cc.y
           + __expf((x.z - mm) * INV_EPS) * cc.z
           + __expf((x.w - mm) * INV_EPS) * cc.w;
      }
      e = wsum(e);
      if (lane == 0) {
        float u = ws_u[row];
        float sp = fmaxf(u * ws_r[row], TINYF);
        float us = u / sp;
        float w = us * e;
        ws_A[row] = us / fmaxf(w, TINYF);
      }
    }
  }
}

// ---------------------------------------------------------------------------
// Fused loss/entropy/qmax pass (persist layout: m@0, A@4096, C@8192)
// ---------------------------------------------------------------------------
__global__ __launch_bounds__(256) void loss_kernel(
    Ptr8 ptrs, const int* __restrict__ iap, const int* __restrict__ ibp,
    const float* __restrict__ wsa, const float* __restrict__ wsb,
    float* __restrict__ out)
{
  const int ia = (*iap) & 7;
  const int ib = (*ibp) & 7;
  const int lane = threadIdx.x & 63;
  const int row = blockIdx.x * 4 + (threadIdx.x >> 6);

  const float ma = wsa[row];
  const float Aa = wsa[4096 + row];
  const float mb = wsb[row];
  const float Ab = wsb[4096 + row];
  const float4* Ca4 = (const float4*)(wsa + 8192);
  const float4* Cb4 = (const float4*)(wsb + 8192);
  size_t off = (size_t)row * Kn;
  const float4* X4[8];
#pragma unroll
  for (int c = 0; c < 8; ++c) X4[c] = (const float4*)(ptrs.p[c] + off);
  const float4* xa4 = (const float4*)(ptrs.p[ia] + off);
  const float4* xb4 = (const float4*)(ptrs.p[ib] + off);

  float M[8], S[8], da[8], db[8];
#pragma unroll
  for (int c = 0; c < 8; ++c) { M[c] = -INFINITY; S[c] = 0.f; da[c] = 0.f; db[c] = 0.f; }
  float enta = 0.f, entb = 0.f, ra = 0.f, rb = 0.f, qam = 0.f, qbm = 0.f;

  for (int i = lane; i < KQ4; i += 64) {
    float4 xa = xa4[i], xb = xb4[i];
    float4 ca = Ca4[i], cb = Cb4[i];
    float qa0 = __expf((xa.x - ma) * INV_EPS) * Aa * ca.x;
    float qa1 = __expf((xa.y - ma) * INV_EPS) * Aa * ca.y;
    float qa2 = __expf((xa.z - ma) * INV_EPS) * Aa * ca.z;
    float qa3 = __expf((xa.w - ma) * INV_EPS) * Aa * ca.w;
    float qb0 = __expf((xb.x - mb) * INV_EPS) * Ab * cb.x;
    float qb1 = __expf((xb.y - mb) * INV_EPS) * Ab * cb.y;
    float qb2 = __expf((xb.z - mb) * INV_EPS) * Ab * cb.z;
    float qb3 = __expf((xb.w - mb) * INV_EPS) * Ab * cb.w;
    ra += (qa0 + qa1) + (qa2 + qa3);
    rb += (qb0 + qb1) + (qb2 + qb3);
    enta += qa0 * __logf(qa0 + TINYF) + qa1 * __logf(qa1 + TINYF)
          + qa2 * __logf(qa2 + TINYF) + qa3 * __logf(qa3 + TINYF);
    entb += qb0 * __logf(qb0 + TINYF) + qb1 * __logf(qb1 + TINYF)
          + qb2 * __logf(qb2 + TINYF) + qb3 * __logf(qb3 + TINYF);
    qam = fmaxf(qam, fmaxf(fmaxf(qa0, qa1), fmaxf(qa2, qa3)));
    qbm = fmaxf(qbm, fmaxf(fmaxf(qb0, qb1), fmaxf(qb2, qb3)));
#pragma unroll
    for (int c = 0; c < 8; ++c) {
      float4 x = X4[c][i];
      float y0 = x.x * INV_TEMP, y1 = x.y * INV_TEMP;
      float y2 = x.z * INV_TEMP, y3 = x.w * INV_TEMP;
      float m4 = fmaxf(fmaxf(y0, y1), fmaxf(y2, y3));
      float t4 = __expf(y0 - m4) + __expf(y1 - m4) + __expf(y2 - m4) + __expf(y3 - m4);
      float Mn = fmaxf(M[c], m4);
      S[c] = S[c] * __expf(M[c] - Mn) + t4 * __expf(m4 - Mn);
      M[c] = Mn;
      da[c] += qa0 * x.x + qa1 * x.y + qa2 * x.z + qa3 * x.w;
      db[c] += qb0 * x.x + qb1 * x.y + qb2 * x.z + qb3 * x.w;
    }
  }

#pragma unroll
  for (int c = 0; c < 8; ++c) {
#pragma unroll
    for (int o = 32; o; o >>= 1) {
      float M2 = __shfl_xor(M[c], o, 64);
      float S2 = __shfl_xor(S[c], o, 64);
      float Mn = fmaxf(M[c], M2);
      S[c] = S[c] * __expf(M[c] - Mn) + S2 * __expf(M2 - Mn);
      M[c] = Mn;
    }
    da[c] = wsum(da[c]);
    db[c] = wsum(db[c]);
  }
  enta = wsum(enta); entb = wsum(entb);
  ra = wsum(ra); rb = wsum(rb);
  qam = wmax(qam); qbm = wmax(qbm);

  if (lane == 0) {
    float lsum = 0.f;
    int nt = 0;
#pragma unroll
    for (int c = 0; c < 8; ++c) {
      float L = M[c] + __logf(S[c]);
      if (c != ia) { lsum -= INV_TEMP * da[c] - L * ra; ++nt; }
      if (c != ib) { lsum -= INV_TEMP * db[c] - L * rb; ++nt; }
    }
    atomicAdd(&out[0], lsum / ((float)nt * (float)Bn));
    atomicAdd(&out[1], -0.5f / (float)Bn * (enta + entb));
    atomicAdd(&out[2], 0.5f / (float)Bn * (qam + qbm));
  }
}

// ---------------------------------------------------------------------------
extern "C" void kernel_launch(void* const* d_in, const int* in_sizes, int n_in,
                              void* d_out, int out_size, void* d_ws, size_t ws_size,
                              hipStream_t stream)
{
  (void)in_sizes; (void)n_in; (void)out_size;
  Ptr8 ptrs;
  for (int c = 0; c < 8; ++c) ptrs.p[c] = (const float*)d_in[c];
  const int* iap = (const int*)d_in[8];
  const int* ibp = (const int*)d_in[9];
  float* ws = (float*)d_ws;
  float* out = (float*)d_out;

  // float-offset layout
  float* PA = ws;                         // m,A,C persist crop a (11264)
  float* PB = ws + 11264;                 // -> 22528
  float* u_ = ws + 22528;                 // [2*Bn] -> 30720
  float* r_ = ws + 30720;                 // [2*Bn] -> 38912
  float* v_ = ws + 38912;                 // [2*KP] -> 45056
  unsigned* rowcnt = (unsigned*)(ws + 45056);   // [2*Bn] -> 53248
  unsigned* colcnt = (unsigned*)(ws + 53248);   // [2*KP] -> 59392
  unsigned* err = (unsigned*)(ws + 59392);      // 512 -> 59904
  unsigned* arrive = (unsigned*)(ws + 59904);   // 64*32 -> 61952
  unsigned* release = (unsigned*)(ws + 61952);  // 64 -> 62016
  float* csrq = ws + 62016;                               // 2*4096*448
  unsigned short* csridx = (unsigned short*)(ws + 3732032);   // u16
  float* cscq = ws + 5567040;                             // 2*3072*448
  unsigned short* cscidx = (unsigned short*)(ws + 8319552);   // u16
  const size_t need_bytes = (size_t)9695808 * 4;          // ~38.8 MB

  // zero colcnt + err + arrive + release (contiguous: 53248..62016)
  hipMemsetAsync(colcnt, 0, 8768 * sizeof(unsigned), stream);
  hipMemsetAsync(d_out, 0, 3 * sizeof(float), stream);

  if (ws_size >= need_bytes) {
    BuildArgs ba;
    ba.ptrs = ptrs; ba.iap = iap; ba.ibp = ibp;
    ba.pmA = PA; ba.pmB = PB;
    ba.r = r_;
    ba.rowcnt = rowcnt; ba.colcnt = colcnt;
    ba.csrq = csrq; ba.csridx = csridx; ba.cscq = cscq; ba.cscidx = cscidx;
    hipLaunchKernelGGL(build_sparse, dim3(BLD_NBLK), dim3(256), 0, stream, ba);

    ItArgs ia;
    ia.pAa = PA + 4096; ia.pCa = PA + 8192;
    ia.pAb = PB + 4096; ia.pCb = PB + 8192;
    ia.u = u_; ia.r = r_; ia.v = v_;
    ia.rowcnt = rowcnt; ia.colcnt = colcnt;
    ia.csrq = csrq; ia.csridx = csridx; ia.cscq = cscq; ia.cscidx = cscidx;
    ia.err = err; ia.arrive = arrive; ia.release = release;
    void* args1[] = { (void*)&ia };
    hipLaunchCooperativeKernel((const void*)sinkhorn_iterate, dim3(IT_NBLK), dim3(IT_THR),
                               (void**)args1, 0u, stream);
  } else {
    // dense fallback (round-0 path); cpart reuses the csrq region start
    float* cpart = ws + 62016;   // NCH*KP = 122880 floats
    unsigned* errA = err;
    unsigned* errB = err + 256;
    {
      float* m = PA; float* A = PA + 4096; float* C = PA + 8192;
      void* args[] = { (void*)&ptrs, (void*)&iap, (void*)&m, (void*)&u_, (void*)&r_,
                       (void*)&A, (void*)&v_, (void*)&C, (void*)&cpart, (void*)&errA };
      hipLaunchCooperativeKernel((const void*)sinkhorn_dense, dim3(GRID_S), dim3(256),
                                 (void**)args, 0u, stream);
    }
    {
      float* m = PB; float* A = PB + 4096; float* C = PB + 8192;
      void* args[] = { (void*)&ptrs, (void*)&ibp, (void*)&m, (void*)&u_, (void*)&r_,
                       (void*)&A, (void*)&v_, (void*)&C, (void*)&cpart, (void*)&errB };
      hipLaunchCooperativeKernel((const void*)sinkhorn_dense, dim3(GRID_S), dim3(256),
                                 (void**)args, 0u, stream);
    }
  }

  loss_kernel<<<dim3(Bn / 4), dim3(256), 0, stream>>>(ptrs, iap, ibp, PA, PB, out);
}